// Round 5
// baseline (235.981 us; speedup 1.0000x reference)
//
#include <hip/hip_runtime.h>

#define BATCH 100000

typedef float v2 __attribute__((ext_vector_type(2)));

__device__ __forceinline__ v2 fma2(v2 a, v2 b, v2 c) { return __builtin_elementwise_fma(a, b, c); }
__device__ __forceinline__ v2 relu2(v2 a) { v2 z = {0.f, 0.f}; return __builtin_elementwise_max(a, z); }
__device__ __forceinline__ v2 splat(float a) { v2 r = {a, a}; return r; }
__device__ __forceinline__ v2 ldv2(const float* p) { return *(const v2*)p; }

// R13 = R11 structure + ALL WEIGHTS IN LDS.
// Post-mortem series R8/R11/R12 (56/52/55 us): SMEM-throughput theory dead
// (R12 halved total scalar traffic, no change); wave-count theory dead
// (R12 at 1.5 waves/SIMD not worse than R8 at 3). Shared invariant:
// per-wave SERIAL scalar-miss chain -- each weight chunk is s_load
// (~300 cy, 17 KB set thrashes the 16 KB K$ shared across CUs) ->
// lgkmcnt(0) -> ~128 cy dependent compute, and ~102 SGPRs can only
// prefetch one chunk ahead. Fix: weights live in LDS (17.1 KB, copied
// once per block); weight reads become ds_read_b64 broadcast
// (wave-uniform addr: conflict-free, ~120 cy, pipelined via immediate
// offsets, no SGPR window, no K$). x global reads overlap the copy.
// Structure unchanged from R11: block 256 = 2 pairs; wave h owns hidden
// [32h,32h+32) of every MLP; sample split across 2 lanes (t); grid 1563.
// LDS 25.3 KB (weights + reused combine scratch) -> 6 blocks/CU = grid's
// 6.1. launch_bounds(256,5): VGPR cap 102 (R11 used 60; ds_read windows
// add some). Spill tripwire: WRITE_SIZE jump (R3/R6/R9).
// readfirstlane(h) kept (R11 lesson: divergent-looking weight addressing
// is catastrophic).

// ---- LDS weight blob layout (dword offsets, all 16B-aligned) ----
#define PW1 0       // phi_w1  4x64   = 256
#define PB1 256     // phi_b1  64
#define PW2 320     // phi_w2  64x16  = 1024
#define PB2 1344    // phi_b2  16
#define QW1 1360    // obs_w1  2x64   = 128
#define QB1 1488    // obs_b1  64
#define QW2 1552    // obs_w2  64x16  = 1024
#define QB2 2576    // obs_b2  16
#define RW1 2592    // rho_w1  16x64  = 1024
#define RB1 3616    // rho_b1  64
#define RW2 3680    // rho_w2  64x2   = 128
#define RB2 3808    // rho_b2  2   (+2 pad)
#define SW1 3812    // psi_w1  4x64   = 256
#define SB1 4068    // psi_b1  64
#define SW2 4132    // psi_w2  64x2   = 128
#define SB2 4260    // psi_b2  2
#define WTOT 4272

__global__ __launch_bounds__(256, 5) void barrier_net(
    const float* __restrict__ x,
    const float* __restrict__ phi_w1, const float* __restrict__ phi_b1,
    const float* __restrict__ phi_w2, const float* __restrict__ phi_b2,
    const float* __restrict__ obs_w1, const float* __restrict__ obs_b1,
    const float* __restrict__ obs_w2, const float* __restrict__ obs_b2,
    const float* __restrict__ rho_w1, const float* __restrict__ rho_b1,
    const float* __restrict__ rho_w2, const float* __restrict__ rho_b2,
    const float* __restrict__ psi_w1, const float* __restrict__ psi_b1,
    const float* __restrict__ psi_w2, const float* __restrict__ psi_b2,
    float2* __restrict__ out)
{
    __shared__ float W[WTOT];
    // Combine scratch, region-reused (extra sync guards the alias):
    //   phase 1: acc  [2pairs*2h][32kk][16]  = dwords [0,2048)
    //   phase 2: rr   [2*2][32][2]           = dwords [0,256)
    //            ee   [2][32][2]             = dwords [256,384)
    __shared__ float S[2048];

    // ---- cooperative weight copy (global x loads below overlap this) ----
#define CPY(off, src, n) \
    for (int i = threadIdx.x; i < (n); i += 256) W[(off) + i] = (src)[i];
    CPY(PW1, phi_w1, 256)  CPY(PB1, phi_b1, 64)
    CPY(PW2, phi_w2, 1024) CPY(PB2, phi_b2, 16)
    CPY(QW1, obs_w1, 128)  CPY(QB1, obs_b1, 64)
    CPY(QW2, obs_w2, 1024) CPY(QB2, obs_b2, 16)
    CPY(RW1, rho_w1, 1024) CPY(RB1, rho_b1, 64)
    CPY(RW2, rho_w2, 128)  CPY(RB2, rho_b2, 2)
    CPY(SW1, psi_w1, 256)  CPY(SB1, psi_b1, 64)
    CPY(SW2, psi_w2, 128)  CPY(SB2, psi_b2, 2)
#undef CPY

    const int lane = threadIdx.x & 63;
    const int wave = threadIdx.x >> 6;
    const int pair = wave >> 1;
    const int h    = wave & 1;       // hidden half owned by this wave
    const int kk   = lane >> 1;      // sample index within the pair-group
    const int t    = lane & 1;       // lane half within the sample
    int s = blockIdx.x * 64 + pair * 32 + kk;
    const bool valid = (s < BATCH);
    if (!valid) s = BATCH - 1;       // clamp: keep loads in-bounds, stay for syncs
    const float* xr = x + (size_t)s * 85;

    // ---- per-lane slice: 8 neighbors (VMEM; overlaps weight copy) ----
    float nb[8][4];
    const int nbase = 5 + 32 * t;
#pragma unroll
    for (int n = 0; n < 8; ++n)
#pragma unroll
        for (int k = 0; k < 4; ++k)
            nb[n][k] = xr[nbase + 4 * n + k];

    float ob[4][2];
    const int obase = 69 + 8 * t;
#pragma unroll
    for (int o = 0; o < 4; ++o) {
        ob[o][0] = xr[obase + 2 * o];
        ob[o][1] = xr[obase + 2 * o + 1];
    }
    const float g0 = xr[0], g1 = xr[1];

    // ---- barrier partial: wave 0 only ----
    float bar0 = 0.f, bar1 = 0.f;
    const int hu = __builtin_amdgcn_readfirstlane(h);
    if (hu == 0) {
#pragma unroll
        for (int n = 0; n < 8; ++n) {
            float p0 = -nb[n][0], p1 = -nb[n][1];
            float r  = __builtin_amdgcn_sqrtf(fmaf(p0, p0, p1 * p1));
            float sc = 0.01f * __builtin_amdgcn_rcpf(r - 0.2f);
            bar0 = fmaf(sc, p0, bar0);
            bar1 = fmaf(sc, p1, bar1);
        }
        bar0 += __shfl_xor(bar0, 1);
        bar1 += __shfl_xor(bar1, 1);
    }

    __syncthreads();   // weights staged

    // ---- uniform hidden-slice base pointers into LDS ----
    const int HB = hu * 32;
    const float* pw1 = W + PW1 + HB;                 // row stride 64
    const float* pb1 = W + PB1 + HB;
    const float* pw2 = W + PW2 + HB * 16;            // W2 row slice
    const float* qw1 = W + QW1 + HB;
    const float* qb1 = W + QB1 + HB;
    const float* qw2 = W + QW2 + HB * 16;
    const float* rw1 = W + RW1 + HB;                 // row stride 64
    const float* rb1 = W + RB1 + HB;
    const float* rw2 = W + RW2 + HB * 2;
    const float* sw1 = W + SW1 + HB;
    const float* sb1 = W + SB1 + HB;
    const float* sw2 = W + SW2 + HB * 2;

    // ---- acc partial: each of the 4 units carries 1/4 of the bias totals ----
    v2 acc[8];
#pragma unroll
    for (int p = 0; p < 8; ++p)
        acc[p] = fma2(splat(4.f), ldv2(W + PB2 + 2 * p),
                 fma2(splat(2.f), ldv2(W + QB2 + 2 * p), splat(0.f)));

    // ---- phi: 4 chunks of 8 hidden ----
#pragma unroll 2
    for (int c = 0; c < 4; ++c) {
        const int hb = 8 * c;
        v2 hsv[4] = {{0.f,0.f},{0.f,0.f},{0.f,0.f},{0.f,0.f}};
#pragma unroll
        for (int n = 0; n < 8; ++n) {
#pragma unroll
            for (int p = 0; p < 4; ++p) {
                v2 tv = fma2(splat(nb[n][0]), ldv2(pw1 + hb + 2 * p),
                        fma2(splat(nb[n][1]), ldv2(pw1 + 64 + hb + 2 * p),
                        fma2(splat(nb[n][2]), ldv2(pw1 + 128 + hb + 2 * p),
                        fma2(splat(nb[n][3]), ldv2(pw1 + 192 + hb + 2 * p),
                                              ldv2(pb1 + hb + 2 * p)))));
                hsv[p] += relu2(tv);
            }
        }
#pragma unroll
        for (int p = 0; p < 4; ++p) {
            const float* r0 = pw2 + (hb + 2 * p) * 16;
            v2 hx = splat(hsv[p].x), hy = splat(hsv[p].y);
#pragma unroll
            for (int q = 0; q < 8; ++q)
                acc[q] = fma2(hy, ldv2(r0 + 16 + 2 * q),
                         fma2(hx, ldv2(r0 + 2 * q), acc[q]));
        }
    }

    // ---- obs: same chunking ----
#pragma unroll 2
    for (int c = 0; c < 4; ++c) {
        const int hb = 8 * c;
        v2 hsv[4] = {{0.f,0.f},{0.f,0.f},{0.f,0.f},{0.f,0.f}};
#pragma unroll
        for (int o = 0; o < 4; ++o) {
#pragma unroll
            for (int p = 0; p < 4; ++p) {
                v2 tv = fma2(splat(ob[o][0]), ldv2(qw1 + hb + 2 * p),
                        fma2(splat(ob[o][1]), ldv2(qw1 + 64 + hb + 2 * p),
                                              ldv2(qb1 + hb + 2 * p)));
                hsv[p] += relu2(tv);
            }
        }
#pragma unroll
        for (int p = 0; p < 4; ++p) {
            const float* r0 = qw2 + (hb + 2 * p) * 16;
            v2 hx = splat(hsv[p].x), hy = splat(hsv[p].y);
#pragma unroll
            for (int q = 0; q < 8; ++q)
                acc[q] = fma2(hy, ldv2(r0 + 16 + 2 * q),
                         fma2(hx, ldv2(r0 + 2 * q), acc[q]));
        }
    }

    // ---- combine across the lane pair (t) ----
#pragma unroll
    for (int p = 0; p < 8; ++p) {
        acc[p].x += __shfl_xor(acc[p].x, 1);
        acc[p].y += __shfl_xor(acc[p].y, 1);
    }

    // ---- combine across the wave pair (h) via S (static acc idx only) ----
    {
        float* slot = S + ((pair * 2 + h) * 32 + kk) * 16 + 8 * t;
#pragma unroll
        for (int p = 0; p < 4; ++p) {
            v2 lo = acc[p], hi = acc[p + 4];
            v2 sel;
            sel.x = t ? hi.x : lo.x;
            sel.y = t ? hi.y : lo.y;
            *(v2*)(slot + 2 * p) = sel;
        }
    }
    __syncthreads();
    {
        const float* oslot = S + ((pair * 2 + (h ^ 1)) * 32 + kk) * 16;
#pragma unroll
        for (int p = 0; p < 8; ++p)
            acc[p] += ldv2(oslot + 2 * p);
    }
    __syncthreads();   // guard: S acc-region reads done before rr reuse

    // ---- rho: 16 -> hidden slice -> 2 (partial) ----
    v2 rr = (hu == 0) ? ldv2(W + RB2) : splat(0.f);
#pragma unroll 2
    for (int c = 0; c < 4; ++c) {
        const int hb = 8 * c;
        v2 tt[4];
#pragma unroll
        for (int p = 0; p < 4; ++p)
            tt[p] = ldv2(rb1 + hb + 2 * p);
#pragma unroll
        for (int j = 0; j < 8; ++j) {
            v2 ax = splat(acc[j].x), ay = splat(acc[j].y);
            const float* rj0 = rw1 + (2 * j) * 64 + hb;
            const float* rj1 = rw1 + (2 * j + 1) * 64 + hb;
#pragma unroll
            for (int p = 0; p < 4; ++p)
                tt[p] = fma2(ay, ldv2(rj1 + 2 * p),
                        fma2(ax, ldv2(rj0 + 2 * p), tt[p]));
        }
#pragma unroll
        for (int p = 0; p < 4; ++p) {
            v2 u = relu2(tt[p]);
            rr = fma2(splat(u.x), ldv2(rw2 + 2 * (hb + 2 * p)), rr);
            rr = fma2(splat(u.y), ldv2(rw2 + 2 * (hb + 2 * p) + 2), rr);
        }
    }
    S[((pair * 2 + h) * 32 + kk) * 2 + t] = t ? rr.y : rr.x;
    __syncthreads();
    rr += ldv2(S + ((pair * 2 + (h ^ 1)) * 32 + kk) * 2);

    // ---- psi: [r0, r1, g0, g1] -> hidden slice -> 2 (partial) ----
    v2 ee = (hu == 0) ? ldv2(W + SB2) : splat(0.f);
#pragma unroll 2
    for (int c = 0; c < 4; ++c) {
        const int hb = 8 * c;
#pragma unroll
        for (int p = 0; p < 4; ++p) {
            v2 tv = fma2(splat(rr.x), ldv2(sw1 + hb + 2 * p),
                    fma2(splat(rr.y), ldv2(sw1 + 64 + hb + 2 * p),
                    fma2(splat(g0),   ldv2(sw1 + 128 + hb + 2 * p),
                    fma2(splat(g1),   ldv2(sw1 + 192 + hb + 2 * p),
                                      ldv2(sb1 + hb + 2 * p)))));
            v2 u = relu2(tv);
            ee = fma2(splat(u.x), ldv2(sw2 + 2 * (hb + 2 * p)), ee);
            ee = fma2(splat(u.y), ldv2(sw2 + 2 * (hb + 2 * p) + 2), ee);
        }
    }
    if (hu == 1)
        S[256 + (pair * 32 + kk) * 2 + t] = t ? ee.y : ee.x;
    __syncthreads();

    if (hu == 0 && t == 0 && valid) {
        v2 eo = ldv2(S + 256 + (pair * 32 + kk) * 2);
        float a0 = tanhf(tanhf(ee.x + eo.x) + bar0);
        float a1 = tanhf(tanhf(ee.y + eo.y) + bar1);
        out[s] = make_float2(2.f * a0, 2.f * a1);
    }
}

extern "C" void kernel_launch(void* const* d_in, const int* in_sizes, int n_in,
                              void* d_out, int out_size, void* d_ws, size_t ws_size,
                              hipStream_t stream) {
    dim3 grid((BATCH + 63) / 64), block(256);   // 64 samples per block
    barrier_net<<<grid, block, 0, stream>>>(
        (const float*)d_in[0],
        (const float*)d_in[1],  (const float*)d_in[2],  (const float*)d_in[3],  (const float*)d_in[4],
        (const float*)d_in[5],  (const float*)d_in[6],  (const float*)d_in[7],  (const float*)d_in[8],
        (const float*)d_in[9],  (const float*)d_in[10], (const float*)d_in[11], (const float*)d_in[12],
        (const float*)d_in[13], (const float*)d_in[14], (const float*)d_in[15], (const float*)d_in[16],
        (float2*)d_out);
}

// Round 6
// 155.281 us; speedup vs baseline: 1.5197x; 1.5197x over previous
//
#include <hip/hip_runtime.h>

#define BATCH 100000

typedef float v2 __attribute__((ext_vector_type(2)));

__device__ __forceinline__ v2 fma2(v2 a, v2 b, v2 c) { return __builtin_elementwise_fma(a, b, c); }
__device__ __forceinline__ v2 relu2(v2 a) { v2 z = {0.f, 0.f}; return __builtin_elementwise_max(a, z); }
__device__ __forceinline__ v2 splat(float a) { v2 r = {a, a}; return r; }
__device__ __forceinline__ v2 ldv2(const float* p) { return *(const v2*)p; }

// R14 = R13 (weights in LDS) with the register-pressure disaster fixed.
// R13 post-mortem: WRITE 222 MB / VGPR_Count 48 = array demotion again.
// Cause: launch_bounds(256,5) caps VGPR at ~96, but the live set is ~110
// (nb 32 + ob 8 + acc 16 + hsv/tt 16 + 12 LDS base VGPRs -- ds_read
// addresses are VGPRs, unlike R11's SGPR s_load bases -- + temps), and
// the `#pragma unroll 2` c-loops keep hb runtime -> live address math
// per access. Fixes:
//  (1) launch_bounds(256,4): cap 128 >= ~110 live.
//  (2) FULL unroll of all c-loops: every weight access = base VGPR +
//      compile-time immediate (ds_read offset:N), ~4 base VGPRs total,
//      and clang merges adjacent reads to ds_read_b128.
//  (3) ob[] loaded after phi (peak-pressure shave).
// This is the first clean test of LDS-weights: broadcast ds_read
// (wave-uniform addr, conflict-free), no K$ thrash, no SGPR-window
// serialization. Structure unchanged from R11/R13: block 256 = 2 pairs;
// wave h owns hidden [32h,32h+32); sample split across 2 lanes (t).
// Spill tripwire: WRITE_SIZE jump (R3/R6/R9/R13). readfirstlane(h) kept.

// ---- LDS weight blob layout (dword offsets, all 16B-aligned) ----
#define PW1 0       // phi_w1  4x64   = 256
#define PB1 256     // phi_b1  64
#define PW2 320     // phi_w2  64x16  = 1024
#define PB2 1344    // phi_b2  16
#define QW1 1360    // obs_w1  2x64   = 128
#define QB1 1488    // obs_b1  64
#define QW2 1552    // obs_w2  64x16  = 1024
#define QB2 2576    // obs_b2  16
#define RW1 2592    // rho_w1  16x64  = 1024
#define RB1 3616    // rho_b1  64
#define RW2 3680    // rho_w2  64x2   = 128
#define RB2 3808    // rho_b2  2   (+2 pad)
#define SW1 3812    // psi_w1  4x64   = 256
#define SB1 4068    // psi_b1  64
#define SW2 4132    // psi_w2  64x2   = 128
#define SB2 4260    // psi_b2  2
#define WTOT 4272

__global__ __launch_bounds__(256, 4) void barrier_net(
    const float* __restrict__ x,
    const float* __restrict__ phi_w1, const float* __restrict__ phi_b1,
    const float* __restrict__ phi_w2, const float* __restrict__ phi_b2,
    const float* __restrict__ obs_w1, const float* __restrict__ obs_b1,
    const float* __restrict__ obs_w2, const float* __restrict__ obs_b2,
    const float* __restrict__ rho_w1, const float* __restrict__ rho_b1,
    const float* __restrict__ rho_w2, const float* __restrict__ rho_b2,
    const float* __restrict__ psi_w1, const float* __restrict__ psi_b1,
    const float* __restrict__ psi_w2, const float* __restrict__ psi_b2,
    float2* __restrict__ out)
{
    __shared__ float W[WTOT];
    // Combine scratch, region-reused (extra sync guards the alias):
    //   phase 1: acc  [2pairs*2h][32kk][16]  = dwords [0,2048)
    //   phase 2: rr   [2*2][32][2]           = dwords [0,256)
    //            ee   [2][32][2]             = dwords [256,384)
    __shared__ float S[2048];

    // ---- cooperative weight copy (global x loads below overlap this) ----
#define CPY(off, src, n) \
    for (int i = threadIdx.x; i < (n); i += 256) W[(off) + i] = (src)[i];
    CPY(PW1, phi_w1, 256)  CPY(PB1, phi_b1, 64)
    CPY(PW2, phi_w2, 1024) CPY(PB2, phi_b2, 16)
    CPY(QW1, obs_w1, 128)  CPY(QB1, obs_b1, 64)
    CPY(QW2, obs_w2, 1024) CPY(QB2, obs_b2, 16)
    CPY(RW1, rho_w1, 1024) CPY(RB1, rho_b1, 64)
    CPY(RW2, rho_w2, 128)  CPY(RB2, rho_b2, 2)
    CPY(SW1, psi_w1, 256)  CPY(SB1, psi_b1, 64)
    CPY(SW2, psi_w2, 128)  CPY(SB2, psi_b2, 2)
#undef CPY

    const int lane = threadIdx.x & 63;
    const int wave = threadIdx.x >> 6;
    const int pair = wave >> 1;
    const int h    = wave & 1;       // hidden half owned by this wave
    const int kk   = lane >> 1;      // sample index within the pair-group
    const int t    = lane & 1;       // lane half within the sample
    int s = blockIdx.x * 64 + pair * 32 + kk;
    const bool valid = (s < BATCH);
    if (!valid) s = BATCH - 1;       // clamp: keep loads in-bounds, stay for syncs
    const float* xr = x + (size_t)s * 85;

    // ---- per-lane slice: 8 neighbors (VMEM; overlaps weight copy) ----
    float nb[8][4];
    const int nbase = 5 + 32 * t;
#pragma unroll
    for (int n = 0; n < 8; ++n)
#pragma unroll
        for (int k = 0; k < 4; ++k)
            nb[n][k] = xr[nbase + 4 * n + k];

    const float g0 = xr[0], g1 = xr[1];

    // ---- barrier partial: wave 0 only ----
    float bar0 = 0.f, bar1 = 0.f;
    const int hu = __builtin_amdgcn_readfirstlane(h);
    if (hu == 0) {
#pragma unroll
        for (int n = 0; n < 8; ++n) {
            float p0 = -nb[n][0], p1 = -nb[n][1];
            float r  = __builtin_amdgcn_sqrtf(fmaf(p0, p0, p1 * p1));
            float sc = 0.01f * __builtin_amdgcn_rcpf(r - 0.2f);
            bar0 = fmaf(sc, p0, bar0);
            bar1 = fmaf(sc, p1, bar1);
        }
        bar0 += __shfl_xor(bar0, 1);
        bar1 += __shfl_xor(bar1, 1);
    }

    __syncthreads();   // weights staged

    // ---- uniform hidden-slice base pointers into LDS (few bases; all
    //      subsequent offsets are compile-time immediates) ----
    const int HB = hu * 32;
    const float* pw1 = W + PW1 + HB;                 // row stride 64
    const float* pb1 = W + PB1 + HB;
    const float* pw2 = W + PW2 + HB * 16;            // W2 row slice
    const float* qw1 = W + QW1 + HB;
    const float* qb1 = W + QB1 + HB;
    const float* qw2 = W + QW2 + HB * 16;
    const float* rw1 = W + RW1 + HB;                 // row stride 64
    const float* rb1 = W + RB1 + HB;
    const float* rw2 = W + RW2 + HB * 2;
    const float* sw1 = W + SW1 + HB;
    const float* sb1 = W + SB1 + HB;
    const float* sw2 = W + SW2 + HB * 2;

    // ---- acc partial: each of the 4 units carries 1/4 of the bias totals ----
    v2 acc[8];
#pragma unroll
    for (int p = 0; p < 8; ++p)
        acc[p] = fma2(splat(4.f), ldv2(W + PB2 + 2 * p),
                 fma2(splat(2.f), ldv2(W + QB2 + 2 * p), splat(0.f)));

    // ---- phi: 4 chunks of 8 hidden, FULLY unrolled (imm offsets) ----
#pragma unroll
    for (int c = 0; c < 4; ++c) {
        const int hb = 8 * c;
        v2 hsv[4] = {{0.f,0.f},{0.f,0.f},{0.f,0.f},{0.f,0.f}};
#pragma unroll
        for (int n = 0; n < 8; ++n) {
#pragma unroll
            for (int p = 0; p < 4; ++p) {
                v2 tv = fma2(splat(nb[n][0]), ldv2(pw1 + hb + 2 * p),
                        fma2(splat(nb[n][1]), ldv2(pw1 + 64 + hb + 2 * p),
                        fma2(splat(nb[n][2]), ldv2(pw1 + 128 + hb + 2 * p),
                        fma2(splat(nb[n][3]), ldv2(pw1 + 192 + hb + 2 * p),
                                              ldv2(pb1 + hb + 2 * p)))));
                hsv[p] += relu2(tv);
            }
        }
#pragma unroll
        for (int p = 0; p < 4; ++p) {
            const float* r0 = pw2 + (hb + 2 * p) * 16;
            v2 hx = splat(hsv[p].x), hy = splat(hsv[p].y);
#pragma unroll
            for (int q = 0; q < 8; ++q)
                acc[q] = fma2(hy, ldv2(r0 + 16 + 2 * q),
                         fma2(hx, ldv2(r0 + 2 * q), acc[q]));
        }
    }

    // ---- per-lane slice: 4 observations (after phi: lower reg peak) ----
    float ob[4][2];
    const int obase = 69 + 8 * t;
#pragma unroll
    for (int o = 0; o < 4; ++o) {
        ob[o][0] = xr[obase + 2 * o];
        ob[o][1] = xr[obase + 2 * o + 1];
    }

    // ---- obs: same chunking, fully unrolled ----
#pragma unroll
    for (int c = 0; c < 4; ++c) {
        const int hb = 8 * c;
        v2 hsv[4] = {{0.f,0.f},{0.f,0.f},{0.f,0.f},{0.f,0.f}};
#pragma unroll
        for (int o = 0; o < 4; ++o) {
#pragma unroll
            for (int p = 0; p < 4; ++p) {
                v2 tv = fma2(splat(ob[o][0]), ldv2(qw1 + hb + 2 * p),
                        fma2(splat(ob[o][1]), ldv2(qw1 + 64 + hb + 2 * p),
                                              ldv2(qb1 + hb + 2 * p)));
                hsv[p] += relu2(tv);
            }
        }
#pragma unroll
        for (int p = 0; p < 4; ++p) {
            const float* r0 = qw2 + (hb + 2 * p) * 16;
            v2 hx = splat(hsv[p].x), hy = splat(hsv[p].y);
#pragma unroll
            for (int q = 0; q < 8; ++q)
                acc[q] = fma2(hy, ldv2(r0 + 16 + 2 * q),
                         fma2(hx, ldv2(r0 + 2 * q), acc[q]));
        }
    }

    // ---- combine across the lane pair (t) ----
#pragma unroll
    for (int p = 0; p < 8; ++p) {
        acc[p].x += __shfl_xor(acc[p].x, 1);
        acc[p].y += __shfl_xor(acc[p].y, 1);
    }

    // ---- combine across the wave pair (h) via S (static acc idx only) ----
    {
        float* slot = S + ((pair * 2 + h) * 32 + kk) * 16 + 8 * t;
#pragma unroll
        for (int p = 0; p < 4; ++p) {
            v2 lo = acc[p], hi = acc[p + 4];
            v2 sel;
            sel.x = t ? hi.x : lo.x;
            sel.y = t ? hi.y : lo.y;
            *(v2*)(slot + 2 * p) = sel;
        }
    }
    __syncthreads();
    {
        const float* oslot = S + ((pair * 2 + (h ^ 1)) * 32 + kk) * 16;
#pragma unroll
        for (int p = 0; p < 8; ++p)
            acc[p] += ldv2(oslot + 2 * p);
    }
    __syncthreads();   // guard: S acc-region reads done before rr reuse

    // ---- rho: 16 -> hidden slice -> 2 (partial), fully unrolled ----
    v2 rr = (hu == 0) ? ldv2(W + RB2) : splat(0.f);
#pragma unroll
    for (int c = 0; c < 4; ++c) {
        const int hb = 8 * c;
        v2 tt[4];
#pragma unroll
        for (int p = 0; p < 4; ++p)
            tt[p] = ldv2(rb1 + hb + 2 * p);
#pragma unroll
        for (int j = 0; j < 8; ++j) {
            v2 ax = splat(acc[j].x), ay = splat(acc[j].y);
            const float* rj0 = rw1 + (2 * j) * 64 + hb;
            const float* rj1 = rw1 + (2 * j + 1) * 64 + hb;
#pragma unroll
            for (int p = 0; p < 4; ++p)
                tt[p] = fma2(ay, ldv2(rj1 + 2 * p),
                        fma2(ax, ldv2(rj0 + 2 * p), tt[p]));
        }
#pragma unroll
        for (int p = 0; p < 4; ++p) {
            v2 u = relu2(tt[p]);
            rr = fma2(splat(u.x), ldv2(rw2 + 2 * (hb + 2 * p)), rr);
            rr = fma2(splat(u.y), ldv2(rw2 + 2 * (hb + 2 * p) + 2), rr);
        }
    }
    S[((pair * 2 + h) * 32 + kk) * 2 + t] = t ? rr.y : rr.x;
    __syncthreads();
    rr += ldv2(S + ((pair * 2 + (h ^ 1)) * 32 + kk) * 2);

    // ---- psi: [r0, r1, g0, g1] -> hidden slice -> 2 (partial) ----
    v2 ee = (hu == 0) ? ldv2(W + SB2) : splat(0.f);
#pragma unroll
    for (int c = 0; c < 4; ++c) {
        const int hb = 8 * c;
#pragma unroll
        for (int p = 0; p < 4; ++p) {
            v2 tv = fma2(splat(rr.x), ldv2(sw1 + hb + 2 * p),
                    fma2(splat(rr.y), ldv2(sw1 + 64 + hb + 2 * p),
                    fma2(splat(g0),   ldv2(sw1 + 128 + hb + 2 * p),
                    fma2(splat(g1),   ldv2(sw1 + 192 + hb + 2 * p),
                                      ldv2(sb1 + hb + 2 * p)))));
            v2 u = relu2(tv);
            ee = fma2(splat(u.x), ldv2(sw2 + 2 * (hb + 2 * p)), ee);
            ee = fma2(splat(u.y), ldv2(sw2 + 2 * (hb + 2 * p) + 2), ee);
        }
    }
    if (hu == 1)
        S[256 + (pair * 32 + kk) * 2 + t] = t ? ee.y : ee.x;
    __syncthreads();

    if (hu == 0 && t == 0 && valid) {
        v2 eo = ldv2(S + 256 + (pair * 32 + kk) * 2);
        float a0 = tanhf(tanhf(ee.x + eo.x) + bar0);
        float a1 = tanhf(tanhf(ee.y + eo.y) + bar1);
        out[s] = make_float2(2.f * a0, 2.f * a1);
    }
}

extern "C" void kernel_launch(void* const* d_in, const int* in_sizes, int n_in,
                              void* d_out, int out_size, void* d_ws, size_t ws_size,
                              hipStream_t stream) {
    dim3 grid((BATCH + 63) / 64), block(256);   // 64 samples per block
    barrier_net<<<grid, block, 0, stream>>>(
        (const float*)d_in[0],
        (const float*)d_in[1],  (const float*)d_in[2],  (const float*)d_in[3],  (const float*)d_in[4],
        (const float*)d_in[5],  (const float*)d_in[6],  (const float*)d_in[7],  (const float*)d_in[8],
        (const float*)d_in[9],  (const float*)d_in[10], (const float*)d_in[11], (const float*)d_in[12],
        (const float*)d_in[13], (const float*)d_in[14], (const float*)d_in[15], (const float*)d_in[16],
        (float2*)d_out);
}

// Round 7
// 150.022 us; speedup vs baseline: 1.5730x; 1.0351x over previous
//
#include <hip/hip_runtime.h>

#define BATCH 100000

typedef float v2 __attribute__((ext_vector_type(2)));

__device__ __forceinline__ v2 fma2(v2 a, v2 b, v2 c) { return __builtin_elementwise_fma(a, b, c); }
__device__ __forceinline__ v2 relu2(v2 a) { v2 z = {0.f, 0.f}; return __builtin_elementwise_max(a, z); }
__device__ __forceinline__ v2 splat(float a) { v2 r = {a, a}; return r; }
__device__ __forceinline__ v2 ldv2(const float* p) { return *(const v2*)p; }

// R15 = R11 skeleton + packed-weights arg + fused phi/obs streams.
// Post-mortem ledger: R13/R14 killed the LDS-weights theory (65 us,
// VALU 37% -- worse than R11's s_load 52 us). Cross-round invariant:
// VALU-busy-time 21-29 us everywhere (tracks executed MACs); idle
// 45-60% everywhere = exposed s_load-chain latency. Two causes:
// (a) prefetch window SGPR-limited: 17 pointer args = 34 SGPRs of the
//     ~102 budget -> ~2 x16 bursts in flight max;
// (b) one serial stream per wave: phi W1 -> phi W2 -> obs W1 -> obs W2,
//     nothing independent to issue during each lgkmcnt wait (W2 chunks:
//     64 streamed dwords vs ~128 cy of dependent FMA).
// Fixes: (1) pack kernel copies all weights into d_ws once -> main
// kernel has 3 pointer args, ~28 SGPRs freed, one base for burst
// merging; (2) phi+obs fused per hidden-chunk: two independent
// weight streams + two FMA chains (hsv/gsv), W2 streams interleaved.
// Structure unchanged from R11 (52.4 us best): block 256 = 2 pairs;
// wave h owns hidden [32h,32h+32); sample split across 2 lanes (t).
// readfirstlane(h) kept (R9/R10 lesson). Spill tripwire: WRITE_SIZE.

// ---- packed weight blob layout (dword offsets) ----
#define PW1 0       // phi_w1  4x64   = 256
#define PB1 256     // phi_b1  64
#define PW2 320     // phi_w2  64x16  = 1024
#define PB2 1344    // phi_b2  16
#define QW1 1360    // obs_w1  2x64   = 128
#define QB1 1488    // obs_b1  64
#define QW2 1552    // obs_w2  64x16  = 1024
#define QB2 2576    // obs_b2  16
#define RW1 2592    // rho_w1  16x64  = 1024
#define RB1 3616    // rho_b1  64
#define RW2 3680    // rho_w2  64x2   = 128
#define RB2 3808    // rho_b2  2 (+2 pad)
#define SW1 3812    // psi_w1  4x64   = 256
#define SB1 4068    // psi_b1  64
#define SW2 4132    // psi_w2  64x2   = 128
#define SB2 4260    // psi_b2  2
#define WTOT 4272

__global__ void pack_weights(
    const float* __restrict__ phi_w1, const float* __restrict__ phi_b1,
    const float* __restrict__ phi_w2, const float* __restrict__ phi_b2,
    const float* __restrict__ obs_w1, const float* __restrict__ obs_b1,
    const float* __restrict__ obs_w2, const float* __restrict__ obs_b2,
    const float* __restrict__ rho_w1, const float* __restrict__ rho_b1,
    const float* __restrict__ rho_w2, const float* __restrict__ rho_b2,
    const float* __restrict__ psi_w1, const float* __restrict__ psi_b1,
    const float* __restrict__ psi_w2, const float* __restrict__ psi_b2,
    float* __restrict__ w)
{
#define CPY(off, src, n) \
    for (int i = threadIdx.x; i < (n); i += 256) w[(off) + i] = (src)[i];
    CPY(PW1, phi_w1, 256)  CPY(PB1, phi_b1, 64)
    CPY(PW2, phi_w2, 1024) CPY(PB2, phi_b2, 16)
    CPY(QW1, obs_w1, 128)  CPY(QB1, obs_b1, 64)
    CPY(QW2, obs_w2, 1024) CPY(QB2, obs_b2, 16)
    CPY(RW1, rho_w1, 1024) CPY(RB1, rho_b1, 64)
    CPY(RW2, rho_w2, 128)  CPY(RB2, rho_b2, 2)
    CPY(SW1, psi_w1, 256)  CPY(SB1, psi_b1, 64)
    CPY(SW2, psi_w2, 128)  CPY(SB2, psi_b2, 2)
#undef CPY
}

__global__ __launch_bounds__(256, 4) void barrier_net(
    const float* __restrict__ x,
    const float* __restrict__ w,
    float2* __restrict__ out)
{
    // Combine scratch (region-reused; extra sync guards the alias):
    //   phase 1: acc [2pairs*2h][32kk][16] = dwords [0,2048)
    //   phase 2: rr  [2*2][32][2] = [0,256); ee [2][32][2] = [256,384)
    __shared__ float S[2048];

    const int lane = threadIdx.x & 63;
    const int wave = threadIdx.x >> 6;
    const int pair = wave >> 1;
    const int h    = wave & 1;       // hidden half owned by this wave
    const int kk   = lane >> 1;      // sample index within the pair-group
    const int t    = lane & 1;       // lane half within the sample
    int s = blockIdx.x * 64 + pair * 32 + kk;
    const bool valid = (s < BATCH);
    if (!valid) s = BATCH - 1;       // clamp: keep loads in-bounds, stay for syncs
    const float* xr = x + (size_t)s * 85;

    // ---- uniform hidden-slice base pointers (readfirstlane: R9/R10) ----
    const int HB = __builtin_amdgcn_readfirstlane(h) * 32;
    const int hu = HB >> 5;
    const float* pw1 = w + PW1 + HB;                 // row stride 64
    const float* pb1 = w + PB1 + HB;
    const float* pw2 = w + PW2 + (size_t)HB * 16;    // W2 row slice
    const float* qw1 = w + QW1 + HB;
    const float* qb1 = w + QB1 + HB;
    const float* qw2 = w + QW2 + (size_t)HB * 16;
    const float* rw1 = w + RW1 + HB;                 // row stride 64
    const float* rb1 = w + RB1 + HB;
    const float* rw2 = w + RW2 + (size_t)HB * 2;
    const float* sw1 = w + SW1 + HB;
    const float* sb1 = w + SB1 + HB;
    const float* sw2 = w + SW2 + (size_t)HB * 2;

    // ---- per-lane slice: 8 neighbors + 4 observations ----
    float nb[8][4];
    const int nbase = 5 + 32 * t;
#pragma unroll
    for (int n = 0; n < 8; ++n)
#pragma unroll
        for (int k = 0; k < 4; ++k)
            nb[n][k] = xr[nbase + 4 * n + k];

    float ob[4][2];
    const int obase = 69 + 8 * t;
#pragma unroll
    for (int o = 0; o < 4; ++o) {
        ob[o][0] = xr[obase + 2 * o];
        ob[o][1] = xr[obase + 2 * o + 1];
    }
    const float g0 = xr[0], g1 = xr[1];

    // ---- barrier partial: wave 0 only ----
    float bar0 = 0.f, bar1 = 0.f;
    if (hu == 0) {
#pragma unroll
        for (int n = 0; n < 8; ++n) {
            float p0 = -nb[n][0], p1 = -nb[n][1];
            float r  = __builtin_amdgcn_sqrtf(fmaf(p0, p0, p1 * p1));
            float sc = 0.01f * __builtin_amdgcn_rcpf(r - 0.2f);
            bar0 = fmaf(sc, p0, bar0);
            bar1 = fmaf(sc, p1, bar1);
        }
        bar0 += __shfl_xor(bar0, 1);
        bar1 += __shfl_xor(bar1, 1);
    }

    // ---- acc partial: each of the 4 units carries 1/4 of the bias totals ----
    v2 acc[8];
#pragma unroll
    for (int p = 0; p < 8; ++p)
        acc[p] = fma2(splat(4.f), ldv2(w + PB2 + 2 * p),
                 fma2(splat(2.f), ldv2(w + QB2 + 2 * p), splat(0.f)));

    // ---- phi + obs FUSED per hidden chunk: 2 independent weight
    //      streams + 2 independent FMA chains per wait ----
#pragma unroll 2
    for (int c = 0; c < 4; ++c) {
        const int hb = 8 * c;
        v2 hsv[4] = {{0.f,0.f},{0.f,0.f},{0.f,0.f},{0.f,0.f}};
        v2 gsv[4] = {{0.f,0.f},{0.f,0.f},{0.f,0.f},{0.f,0.f}};
#pragma unroll
        for (int n = 0; n < 8; ++n) {
#pragma unroll
            for (int p = 0; p < 4; ++p) {
                v2 tv = fma2(splat(nb[n][0]), ldv2(pw1 + hb + 2 * p),
                        fma2(splat(nb[n][1]), ldv2(pw1 + 64 + hb + 2 * p),
                        fma2(splat(nb[n][2]), ldv2(pw1 + 128 + hb + 2 * p),
                        fma2(splat(nb[n][3]), ldv2(pw1 + 192 + hb + 2 * p),
                                              ldv2(pb1 + hb + 2 * p)))));
                hsv[p] += relu2(tv);
            }
        }
#pragma unroll
        for (int o = 0; o < 4; ++o) {
#pragma unroll
            for (int p = 0; p < 4; ++p) {
                v2 tv = fma2(splat(ob[o][0]), ldv2(qw1 + hb + 2 * p),
                        fma2(splat(ob[o][1]), ldv2(qw1 + 64 + hb + 2 * p),
                                              ldv2(qb1 + hb + 2 * p)));
                gsv[p] += relu2(tv);
            }
        }
        // W2 stage: phi and obs streams interleaved (2 bursts in flight)
#pragma unroll
        for (int p = 0; p < 4; ++p) {
            const float* r0 = pw2 + (size_t)(hb + 2 * p) * 16;
            const float* s0 = qw2 + (size_t)(hb + 2 * p) * 16;
            v2 hx = splat(hsv[p].x), hy = splat(hsv[p].y);
            v2 gx = splat(gsv[p].x), gy = splat(gsv[p].y);
#pragma unroll
            for (int q = 0; q < 8; ++q) {
                acc[q] = fma2(hy, ldv2(r0 + 16 + 2 * q),
                         fma2(hx, ldv2(r0 + 2 * q), acc[q]));
                acc[q] = fma2(gy, ldv2(s0 + 16 + 2 * q),
                         fma2(gx, ldv2(s0 + 2 * q), acc[q]));
            }
        }
    }

    // ---- combine across the lane pair (t) ----
#pragma unroll
    for (int p = 0; p < 8; ++p) {
        acc[p].x += __shfl_xor(acc[p].x, 1);
        acc[p].y += __shfl_xor(acc[p].y, 1);
    }

    // ---- combine across the wave pair (h) via S (static acc idx only) ----
    {
        float* slot = S + ((pair * 2 + h) * 32 + kk) * 16 + 8 * t;
#pragma unroll
        for (int p = 0; p < 4; ++p) {
            v2 lo = acc[p], hi = acc[p + 4];
            v2 sel;
            sel.x = t ? hi.x : lo.x;
            sel.y = t ? hi.y : lo.y;
            *(v2*)(slot + 2 * p) = sel;
        }
    }
    __syncthreads();
    {
        const float* oslot = S + ((pair * 2 + (h ^ 1)) * 32 + kk) * 16;
#pragma unroll
        for (int p = 0; p < 8; ++p)
            acc[p] += ldv2(oslot + 2 * p);
    }
    __syncthreads();   // guard: S acc-region reads done before rr reuse

    // ---- rho: 16 -> hidden slice -> 2 (partial) ----
    v2 rr = (hu == 0) ? ldv2(w + RB2) : splat(0.f);
#pragma unroll 2
    for (int c = 0; c < 4; ++c) {
        const int hb = 8 * c;
        v2 tt[4];
#pragma unroll
        for (int p = 0; p < 4; ++p)
            tt[p] = ldv2(rb1 + hb + 2 * p);
#pragma unroll
        for (int j = 0; j < 8; ++j) {
            v2 ax = splat(acc[j].x), ay = splat(acc[j].y);
            const float* rj0 = rw1 + (size_t)(2 * j) * 64 + hb;
            const float* rj1 = rw1 + (size_t)(2 * j + 1) * 64 + hb;
#pragma unroll
            for (int p = 0; p < 4; ++p)
                tt[p] = fma2(ay, ldv2(rj1 + 2 * p),
                        fma2(ax, ldv2(rj0 + 2 * p), tt[p]));
        }
#pragma unroll
        for (int p = 0; p < 4; ++p) {
            v2 u = relu2(tt[p]);
            rr = fma2(splat(u.x), ldv2(rw2 + 2 * (hb + 2 * p)), rr);
            rr = fma2(splat(u.y), ldv2(rw2 + 2 * (hb + 2 * p) + 2), rr);
        }
    }
    S[((pair * 2 + h) * 32 + kk) * 2 + t] = t ? rr.y : rr.x;
    __syncthreads();
    rr += ldv2(S + ((pair * 2 + (h ^ 1)) * 32 + kk) * 2);

    // ---- psi: [r0, r1, g0, g1] -> hidden slice -> 2 (partial) ----
    v2 ee = (hu == 0) ? ldv2(w + SB2) : splat(0.f);
#pragma unroll 2
    for (int c = 0; c < 4; ++c) {
        const int hb = 8 * c;
#pragma unroll
        for (int p = 0; p < 4; ++p) {
            v2 tv = fma2(splat(rr.x), ldv2(sw1 + hb + 2 * p),
                    fma2(splat(rr.y), ldv2(sw1 + 64 + hb + 2 * p),
                    fma2(splat(g0),   ldv2(sw1 + 128 + hb + 2 * p),
                    fma2(splat(g1),   ldv2(sw1 + 192 + hb + 2 * p),
                                      ldv2(sb1 + hb + 2 * p)))));
            v2 u = relu2(tv);
            ee = fma2(splat(u.x), ldv2(sw2 + 2 * (hb + 2 * p)), ee);
            ee = fma2(splat(u.y), ldv2(sw2 + 2 * (hb + 2 * p) + 2), ee);
        }
    }
    if (hu == 1)
        S[256 + (pair * 32 + kk) * 2 + t] = t ? ee.y : ee.x;
    __syncthreads();

    if (hu == 0 && t == 0 && valid) {
        v2 eo = ldv2(S + 256 + (pair * 32 + kk) * 2);
        float a0 = tanhf(tanhf(ee.x + eo.x) + bar0);
        float a1 = tanhf(tanhf(ee.y + eo.y) + bar1);
        out[s] = make_float2(2.f * a0, 2.f * a1);
    }
}

extern "C" void kernel_launch(void* const* d_in, const int* in_sizes, int n_in,
                              void* d_out, int out_size, void* d_ws, size_t ws_size,
                              hipStream_t stream) {
    float* w = (float*)d_ws;   // 4272 dwords = 17.1 KB of workspace
    pack_weights<<<1, 256, 0, stream>>>(
        (const float*)d_in[1],  (const float*)d_in[2],  (const float*)d_in[3],  (const float*)d_in[4],
        (const float*)d_in[5],  (const float*)d_in[6],  (const float*)d_in[7],  (const float*)d_in[8],
        (const float*)d_in[9],  (const float*)d_in[10], (const float*)d_in[11], (const float*)d_in[12],
        (const float*)d_in[13], (const float*)d_in[14], (const float*)d_in[15], (const float*)d_in[16],
        w);
    dim3 grid((BATCH + 63) / 64), block(256);   // 64 samples per block
    barrier_net<<<grid, block, 0, stream>>>(
        (const float*)d_in[0], w, (float2*)d_out);
}

// Round 8
// 147.332 us; speedup vs baseline: 1.6017x; 1.0183x over previous
//
#include <hip/hip_runtime.h>

#define BATCH 100000

typedef float v2 __attribute__((ext_vector_type(2)));

__device__ __forceinline__ v2 fma2(v2 a, v2 b, v2 c) { return __builtin_elementwise_fma(a, b, c); }
__device__ __forceinline__ v2 relu2(v2 a) { v2 z = {0.f, 0.f}; return __builtin_elementwise_max(a, z); }
__device__ __forceinline__ v2 splat(float a) { v2 r = {a, a}; return r; }
__device__ __forceinline__ v2 ldv2(const float* p) { return *(const v2*)p; }

// R16 = R15's fusion, cleanly tested: pack kernel dropped, spill forced out.
// R15 post-mortem: (a) pack_weights (1-block kernel) serialized ~10 us of
// bench for zero SGPR benefit (SGPR_Count stayed 112 -- kernarg s_loads
// dominate); (b) VGPR_Count=64 with ~90 live = compiler chose
// 64-VGPR-with-spill (WRITE 17.5 MB, ~11 dw/thread) chasing 8 waves/SIMD,
// despite launch_bounds allowing 128. Fixes: 17 original args (no pack);
// amdgpu_waves_per_eu(4,4) pins the occupancy target to exactly 4
// waves/EU so the allocator uses up to 128 VGPRs with NO spill.
// Content kept from R15: phi+obs FUSED per hidden chunk -> two
// independent s_load streams + two FMA chains per lgkmcnt wait.
// Skeleton from R11 (best bench 139.8): block 256 = 2 wave-pairs;
// wave h owns hidden [32h,32h+32) of every MLP; sample split across
// 2 lanes (t); readfirstlane(h) mandatory (R9/R10: divergent-looking
// weight addressing -> per-lane VMEM -> scratch catastrophe).
// Spill tripwire: WRITE_SIZE >> 781 KB.
__global__
__attribute__((amdgpu_flat_work_group_size(256, 256), amdgpu_waves_per_eu(4, 4)))
void barrier_net(
    const float* __restrict__ x,
    const float* __restrict__ phi_w1, const float* __restrict__ phi_b1,
    const float* __restrict__ phi_w2, const float* __restrict__ phi_b2,
    const float* __restrict__ obs_w1, const float* __restrict__ obs_b1,
    const float* __restrict__ obs_w2, const float* __restrict__ obs_b2,
    const float* __restrict__ rho_w1, const float* __restrict__ rho_b1,
    const float* __restrict__ rho_w2, const float* __restrict__ rho_b2,
    const float* __restrict__ psi_w1, const float* __restrict__ psi_b1,
    const float* __restrict__ psi_w2, const float* __restrict__ psi_b2,
    float2* __restrict__ out)
{
    // Combine scratch (region-reused; extra sync guards the alias):
    //   phase 1: acc [2pairs*2h][32kk][16] = dwords [0,2048)
    //   phase 2: rr  [2*2][32][2] = [0,256); ee [2][32][2] = [256,384)
    __shared__ float S[2048];

    const int lane = threadIdx.x & 63;
    const int wave = threadIdx.x >> 6;
    const int pair = wave >> 1;
    const int h    = wave & 1;       // hidden half owned by this wave
    const int kk   = lane >> 1;      // sample index within the pair-group
    const int t    = lane & 1;       // lane half within the sample
    int s = blockIdx.x * 64 + pair * 32 + kk;
    const bool valid = (s < BATCH);
    if (!valid) s = BATCH - 1;       // clamp: keep loads in-bounds, stay for syncs
    const float* xr = x + (size_t)s * 85;

    // ---- uniform hidden-slice base pointers (readfirstlane: R9/R10) ----
    const int HB = __builtin_amdgcn_readfirstlane(h) * 32;
    const int hu = HB >> 5;
    const float* pw1 = phi_w1 + HB;                 // row stride 64
    const float* pb1 = phi_b1 + HB;
    const float* pw2 = phi_w2 + (size_t)HB * 16;    // W2 row slice
    const float* qw1 = obs_w1 + HB;
    const float* qb1 = obs_b1 + HB;
    const float* qw2 = obs_w2 + (size_t)HB * 16;
    const float* rw1 = rho_w1 + HB;                 // row stride 64
    const float* rb1 = rho_b1 + HB;
    const float* rw2 = rho_w2 + (size_t)HB * 2;
    const float* sw1 = psi_w1 + HB;
    const float* sb1 = psi_b1 + HB;
    const float* sw2 = psi_w2 + (size_t)HB * 2;

    // ---- per-lane slice: 8 neighbors + 4 observations ----
    float nb[8][4];
    const int nbase = 5 + 32 * t;
#pragma unroll
    for (int n = 0; n < 8; ++n)
#pragma unroll
        for (int k = 0; k < 4; ++k)
            nb[n][k] = xr[nbase + 4 * n + k];

    float ob[4][2];
    const int obase = 69 + 8 * t;
#pragma unroll
    for (int o = 0; o < 4; ++o) {
        ob[o][0] = xr[obase + 2 * o];
        ob[o][1] = xr[obase + 2 * o + 1];
    }
    const float g0 = xr[0], g1 = xr[1];

    // ---- barrier partial: wave 0 only ----
    float bar0 = 0.f, bar1 = 0.f;
    if (hu == 0) {
#pragma unroll
        for (int n = 0; n < 8; ++n) {
            float p0 = -nb[n][0], p1 = -nb[n][1];
            float r  = __builtin_amdgcn_sqrtf(fmaf(p0, p0, p1 * p1));
            float sc = 0.01f * __builtin_amdgcn_rcpf(r - 0.2f);
            bar0 = fmaf(sc, p0, bar0);
            bar1 = fmaf(sc, p1, bar1);
        }
        bar0 += __shfl_xor(bar0, 1);
        bar1 += __shfl_xor(bar1, 1);
    }

    // ---- acc partial: each of the 4 units carries 1/4 of the bias totals ----
    v2 acc[8];
#pragma unroll
    for (int p = 0; p < 8; ++p)
        acc[p] = fma2(splat(4.f), ldv2(phi_b2 + 2 * p),
                 fma2(splat(2.f), ldv2(obs_b2 + 2 * p), splat(0.f)));

    // ---- phi + obs FUSED per hidden chunk: 2 independent weight
    //      streams + 2 independent FMA chains per wait ----
#pragma unroll 2
    for (int c = 0; c < 4; ++c) {
        const int hb = 8 * c;
        v2 hsv[4] = {{0.f,0.f},{0.f,0.f},{0.f,0.f},{0.f,0.f}};
        v2 gsv[4] = {{0.f,0.f},{0.f,0.f},{0.f,0.f},{0.f,0.f}};
#pragma unroll
        for (int n = 0; n < 8; ++n) {
#pragma unroll
            for (int p = 0; p < 4; ++p) {
                v2 tv = fma2(splat(nb[n][0]), ldv2(pw1 + hb + 2 * p),
                        fma2(splat(nb[n][1]), ldv2(pw1 + 64 + hb + 2 * p),
                        fma2(splat(nb[n][2]), ldv2(pw1 + 128 + hb + 2 * p),
                        fma2(splat(nb[n][3]), ldv2(pw1 + 192 + hb + 2 * p),
                                              ldv2(pb1 + hb + 2 * p)))));
                hsv[p] += relu2(tv);
            }
        }
#pragma unroll
        for (int o = 0; o < 4; ++o) {
#pragma unroll
            for (int p = 0; p < 4; ++p) {
                v2 tv = fma2(splat(ob[o][0]), ldv2(qw1 + hb + 2 * p),
                        fma2(splat(ob[o][1]), ldv2(qw1 + 64 + hb + 2 * p),
                                              ldv2(qb1 + hb + 2 * p)));
                gsv[p] += relu2(tv);
            }
        }
        // W2 stage: phi and obs streams interleaved (2 bursts in flight)
#pragma unroll
        for (int p = 0; p < 4; ++p) {
            const float* r0 = pw2 + (size_t)(hb + 2 * p) * 16;
            const float* s0 = qw2 + (size_t)(hb + 2 * p) * 16;
            v2 hx = splat(hsv[p].x), hy = splat(hsv[p].y);
            v2 gx = splat(gsv[p].x), gy = splat(gsv[p].y);
#pragma unroll
            for (int q = 0; q < 8; ++q) {
                acc[q] = fma2(hy, ldv2(r0 + 16 + 2 * q),
                         fma2(hx, ldv2(r0 + 2 * q), acc[q]));
                acc[q] = fma2(gy, ldv2(s0 + 16 + 2 * q),
                         fma2(gx, ldv2(s0 + 2 * q), acc[q]));
            }
        }
    }

    // ---- combine across the lane pair (t) ----
#pragma unroll
    for (int p = 0; p < 8; ++p) {
        acc[p].x += __shfl_xor(acc[p].x, 1);
        acc[p].y += __shfl_xor(acc[p].y, 1);
    }

    // ---- combine across the wave pair (h) via S (static acc idx only) ----
    {
        float* slot = S + ((pair * 2 + h) * 32 + kk) * 16 + 8 * t;
#pragma unroll
        for (int p = 0; p < 4; ++p) {
            v2 lo = acc[p], hi = acc[p + 4];
            v2 sel;
            sel.x = t ? hi.x : lo.x;
            sel.y = t ? hi.y : lo.y;
            *(v2*)(slot + 2 * p) = sel;
        }
    }
    __syncthreads();
    {
        const float* oslot = S + ((pair * 2 + (h ^ 1)) * 32 + kk) * 16;
#pragma unroll
        for (int p = 0; p < 8; ++p)
            acc[p] += ldv2(oslot + 2 * p);
    }
    __syncthreads();   // guard: S acc-region reads done before rr reuse

    // ---- rho: 16 -> hidden slice -> 2 (partial) ----
    v2 rr = (hu == 0) ? ldv2(rho_b2) : splat(0.f);
#pragma unroll 2
    for (int c = 0; c < 4; ++c) {
        const int hb = 8 * c;
        v2 tt[4];
#pragma unroll
        for (int p = 0; p < 4; ++p)
            tt[p] = ldv2(rb1 + hb + 2 * p);
#pragma unroll
        for (int j = 0; j < 8; ++j) {
            v2 ax = splat(acc[j].x), ay = splat(acc[j].y);
            const float* rj0 = rw1 + (size_t)(2 * j) * 64 + hb;
            const float* rj1 = rw1 + (size_t)(2 * j + 1) * 64 + hb;
#pragma unroll
            for (int p = 0; p < 4; ++p)
                tt[p] = fma2(ay, ldv2(rj1 + 2 * p),
                        fma2(ax, ldv2(rj0 + 2 * p), tt[p]));
        }
#pragma unroll
        for (int p = 0; p < 4; ++p) {
            v2 u = relu2(tt[p]);
            rr = fma2(splat(u.x), ldv2(rw2 + 2 * (hb + 2 * p)), rr);
            rr = fma2(splat(u.y), ldv2(rw2 + 2 * (hb + 2 * p) + 2), rr);
        }
    }
    S[((pair * 2 + h) * 32 + kk) * 2 + t] = t ? rr.y : rr.x;
    __syncthreads();
    rr += ldv2(S + ((pair * 2 + (h ^ 1)) * 32 + kk) * 2);

    // ---- psi: [r0, r1, g0, g1] -> hidden slice -> 2 (partial) ----
    v2 ee = (hu == 0) ? ldv2(psi_b2) : splat(0.f);
#pragma unroll 2
    for (int c = 0; c < 4; ++c) {
        const int hb = 8 * c;
#pragma unroll
        for (int p = 0; p < 4; ++p) {
            v2 tv = fma2(splat(rr.x), ldv2(sw1 + hb + 2 * p),
                    fma2(splat(rr.y), ldv2(sw1 + 64 + hb + 2 * p),
                    fma2(splat(g0),   ldv2(sw1 + 128 + hb + 2 * p),
                    fma2(splat(g1),   ldv2(sw1 + 192 + hb + 2 * p),
                                      ldv2(sb1 + hb + 2 * p)))));
            v2 u = relu2(tv);
            ee = fma2(splat(u.x), ldv2(sw2 + 2 * (hb + 2 * p)), ee);
            ee = fma2(splat(u.y), ldv2(sw2 + 2 * (hb + 2 * p) + 2), ee);
        }
    }
    if (hu == 1)
        S[256 + (pair * 32 + kk) * 2 + t] = t ? ee.y : ee.x;
    __syncthreads();

    if (hu == 0 && t == 0 && valid) {
        v2 eo = ldv2(S + 256 + (pair * 32 + kk) * 2);
        float a0 = tanhf(tanhf(ee.x + eo.x) + bar0);
        float a1 = tanhf(tanhf(ee.y + eo.y) + bar1);
        out[s] = make_float2(2.f * a0, 2.f * a1);
    }
}

extern "C" void kernel_launch(void* const* d_in, const int* in_sizes, int n_in,
                              void* d_out, int out_size, void* d_ws, size_t ws_size,
                              hipStream_t stream) {
    dim3 grid((BATCH + 63) / 64), block(256);   // 64 samples per block
    barrier_net<<<grid, block, 0, stream>>>(
        (const float*)d_in[0],
        (const float*)d_in[1],  (const float*)d_in[2],  (const float*)d_in[3],  (const float*)d_in[4],
        (const float*)d_in[5],  (const float*)d_in[6],  (const float*)d_in[7],  (const float*)d_in[8],
        (const float*)d_in[9],  (const float*)d_in[10], (const float*)d_in[11], (const float*)d_in[12],
        (const float*)d_in[13], (const float*)d_in[14], (const float*)d_in[15], (const float*)d_in[16],
        (float2*)d_out);
}

// Round 9
// 143.870 us; speedup vs baseline: 1.6402x; 1.0241x over previous
//
#include <hip/hip_runtime.h>

#define BATCH 100000

typedef float v2 __attribute__((ext_vector_type(2)));

__device__ __forceinline__ v2 fma2(v2 a, v2 b, v2 c) { return __builtin_elementwise_fma(a, b, c); }
__device__ __forceinline__ v2 relu2(v2 a) { v2 z = {0.f, 0.f}; return __builtin_elementwise_max(a, z); }
__device__ __forceinline__ v2 splat(float a) { v2 r = {a, a}; return r; }
__device__ __forceinline__ v2 ldv2(const float* p) { return *(const v2*)p; }

// R17 = R11 VERBATIM with the four hidden-chunk loops ROLLED (unroll 1).
// Theory: the 52-56 us wall survived six different data-path structures
// (s_load R8/R11, per-lane VMEM R9, LDS weights R14, x-staged R12,
// fused streams R15/R16) -- the only shared property is ~30-50 KB of
// fully-unrolled straight-line code. CDNA shares a 32 KB L1I across a
// 4-CU cluster; waves at different points of a 30+ KB body miss to L2
// (~200 cy / 64 B line) continuously. An instruction-fetch wall is
// insensitive to data-side changes (exactly what we measured) and caps
// VALUBusy ~50%. Rolling the c-loops shrinks hot code to ~8 KB (fits).
// Inner n/p/j/q loops stay unrolled: nb/ob/acc/hsv/tt demand static
// indices (rule #20, R9 lesson). Weight addresses in a rolled loop stay
// uniform-base + SGPR-stepped -> s_load bursts survive.
// Pre-committed read: right -> 33-40 us, VALU 70-85%; wrong -> 54-65 us,
// VALU <=50% and the plateau is declared at R11 next round.
// Tripwires: WRITE ~781 KB, VGPR 60-64, SGPR ~112.
__global__ __launch_bounds__(256, 4) void barrier_net(
    const float* __restrict__ x,
    const float* __restrict__ phi_w1, const float* __restrict__ phi_b1,
    const float* __restrict__ phi_w2, const float* __restrict__ phi_b2,
    const float* __restrict__ obs_w1, const float* __restrict__ obs_b1,
    const float* __restrict__ obs_w2, const float* __restrict__ obs_b2,
    const float* __restrict__ rho_w1, const float* __restrict__ rho_b1,
    const float* __restrict__ rho_w2, const float* __restrict__ rho_b2,
    const float* __restrict__ psi_w1, const float* __restrict__ psi_b1,
    const float* __restrict__ psi_w2, const float* __restrict__ psi_b2,
    float2* __restrict__ out)
{
    __shared__ float accL[2][2][32][16];
    __shared__ float rrL[2][2][32][2];
    __shared__ float eeL[2][2][32][2];

    const int lane = threadIdx.x & 63;
    const int wave = threadIdx.x >> 6;
    const int pair = wave >> 1;
    const int h    = wave & 1;       // hidden half owned by this wave
    const int kk   = lane >> 1;      // sample index within the pair-group
    const int t    = lane & 1;       // lane half within the sample
    int s = blockIdx.x * 64 + pair * 32 + kk;
    const bool valid = (s < BATCH);
    if (!valid) s = BATCH - 1;       // clamp: keep loads in-bounds, stay for syncs
    const float* xr = x + (size_t)s * 85;

    // ---- uniform hidden-slice base pointers (readfirstlane: R9/R10) ----
    const int HB = __builtin_amdgcn_readfirstlane(h) * 32;
    const int hu = HB >> 5;
    const float* pw1 = phi_w1 + HB;                 // row stride 64
    const float* pb1 = phi_b1 + HB;
    const float* pw2 = phi_w2 + (size_t)HB * 16;    // W2 row slice
    const float* qw1 = obs_w1 + HB;
    const float* qb1 = obs_b1 + HB;
    const float* qw2 = obs_w2 + (size_t)HB * 16;
    const float* rw1 = rho_w1 + HB;                 // row stride 64
    const float* rb1 = rho_b1 + HB;
    const float* rw2 = rho_w2 + (size_t)HB * 2;
    const float* sw1 = psi_w1 + HB;
    const float* sb1 = psi_b1 + HB;
    const float* sw2 = psi_w2 + (size_t)HB * 2;

    // ---- per-lane slice: 8 neighbors ----
    float nb[8][4];
    const int nbase = 5 + 32 * t;
#pragma unroll
    for (int n = 0; n < 8; ++n)
#pragma unroll
        for (int k = 0; k < 4; ++k)
            nb[n][k] = xr[nbase + 4 * n + k];

    // ---- barrier partial: wave 0 only (it does the final store) ----
    float bar0 = 0.f, bar1 = 0.f;
    if (hu == 0) {
#pragma unroll
        for (int n = 0; n < 8; ++n) {
            float p0 = -nb[n][0], p1 = -nb[n][1];
            float r  = __builtin_amdgcn_sqrtf(fmaf(p0, p0, p1 * p1));
            float sc = 0.01f * __builtin_amdgcn_rcpf(r - 0.2f);
            bar0 = fmaf(sc, p0, bar0);
            bar1 = fmaf(sc, p1, bar1);
        }
        bar0 += __shfl_xor(bar0, 1);
        bar1 += __shfl_xor(bar1, 1);
    }

    // ---- acc partial: each of the 4 units carries 1/4 of the bias totals ----
    v2 acc[8];
#pragma unroll
    for (int p = 0; p < 8; ++p)
        acc[p] = fma2(splat(4.f), ldv2(phi_b2 + 2 * p),
                 fma2(splat(2.f), ldv2(obs_b2 + 2 * p), splat(0.f)));

    // ---- phi: ROLLED chunk loop (small code; SGPR-stepped s_loads) ----
#pragma unroll 1
    for (int c = 0; c < 4; ++c) {
        const int hb = 8 * c;
        v2 hsv[4] = {{0.f,0.f},{0.f,0.f},{0.f,0.f},{0.f,0.f}};
#pragma unroll
        for (int n = 0; n < 8; ++n) {
#pragma unroll
            for (int p = 0; p < 4; ++p) {
                v2 tv = fma2(splat(nb[n][0]), ldv2(pw1 + hb + 2 * p),
                        fma2(splat(nb[n][1]), ldv2(pw1 + 64 + hb + 2 * p),
                        fma2(splat(nb[n][2]), ldv2(pw1 + 128 + hb + 2 * p),
                        fma2(splat(nb[n][3]), ldv2(pw1 + 192 + hb + 2 * p),
                                              ldv2(pb1 + hb + 2 * p)))));
                hsv[p] += relu2(tv);
            }
        }
#pragma unroll
        for (int p = 0; p < 4; ++p) {
            const float* r0 = pw2 + (size_t)(hb + 2 * p) * 16;
            v2 hx = splat(hsv[p].x), hy = splat(hsv[p].y);
#pragma unroll
            for (int q = 0; q < 8; ++q)
                acc[q] = fma2(hy, ldv2(r0 + 16 + 2 * q),
                         fma2(hx, ldv2(r0 + 2 * q), acc[q]));
        }
    }

    // ---- per-lane slice: 4 observations ----
    float ob[4][2];
    const int obase = 69 + 8 * t;
#pragma unroll
    for (int o = 0; o < 4; ++o) {
        ob[o][0] = xr[obase + 2 * o];
        ob[o][1] = xr[obase + 2 * o + 1];
    }

    // ---- obs: ROLLED chunk loop ----
#pragma unroll 1
    for (int c = 0; c < 4; ++c) {
        const int hb = 8 * c;
        v2 hsv[4] = {{0.f,0.f},{0.f,0.f},{0.f,0.f},{0.f,0.f}};
#pragma unroll
        for (int o = 0; o < 4; ++o) {
#pragma unroll
            for (int p = 0; p < 4; ++p) {
                v2 tv = fma2(splat(ob[o][0]), ldv2(qw1 + hb + 2 * p),
                        fma2(splat(ob[o][1]), ldv2(qw1 + 64 + hb + 2 * p),
                                              ldv2(qb1 + hb + 2 * p)));
                hsv[p] += relu2(tv);
            }
        }
#pragma unroll
        for (int p = 0; p < 4; ++p) {
            const float* r0 = qw2 + (size_t)(hb + 2 * p) * 16;
            v2 hx = splat(hsv[p].x), hy = splat(hsv[p].y);
#pragma unroll
            for (int q = 0; q < 8; ++q)
                acc[q] = fma2(hy, ldv2(r0 + 16 + 2 * q),
                         fma2(hx, ldv2(r0 + 2 * q), acc[q]));
        }
    }

    // ---- combine across the lane pair (t) ----
#pragma unroll
    for (int p = 0; p < 8; ++p) {
        acc[p].x += __shfl_xor(acc[p].x, 1);
        acc[p].y += __shfl_xor(acc[p].y, 1);
    }

    // ---- combine across the wave pair (h) via LDS ----
    {
        float* slot = &accL[pair][h][kk][8 * t];
#pragma unroll
        for (int p = 0; p < 4; ++p) {
            v2 lo = acc[p], hi = acc[p + 4];
            v2 sel;
            sel.x = t ? hi.x : lo.x;
            sel.y = t ? hi.y : lo.y;
            *(v2*)(slot + 2 * p) = sel;
        }
    }
    __syncthreads();
    {
        const float* oslot = &accL[pair][h ^ 1][kk][0];
#pragma unroll
        for (int p = 0; p < 8; ++p)
            acc[p] += ldv2(oslot + 2 * p);
    }

    const float g0 = xr[0], g1 = xr[1];

    // ---- rho: ROLLED chunk loop (j-loop stays unrolled: static acc idx) ----
    v2 rr = (hu == 0) ? ldv2(rho_b2) : splat(0.f);
#pragma unroll 1
    for (int c = 0; c < 4; ++c) {
        const int hb = 8 * c;
        v2 tt[4];
#pragma unroll
        for (int p = 0; p < 4; ++p)
            tt[p] = ldv2(rb1 + hb + 2 * p);
#pragma unroll
        for (int j = 0; j < 8; ++j) {
            v2 ax = splat(acc[j].x), ay = splat(acc[j].y);
            const float* rj0 = rw1 + (size_t)(2 * j) * 64 + hb;
            const float* rj1 = rw1 + (size_t)(2 * j + 1) * 64 + hb;
#pragma unroll
            for (int p = 0; p < 4; ++p)
                tt[p] = fma2(ay, ldv2(rj1 + 2 * p),
                        fma2(ax, ldv2(rj0 + 2 * p), tt[p]));
        }
#pragma unroll
        for (int p = 0; p < 4; ++p) {
            v2 u = relu2(tt[p]);
            rr = fma2(splat(u.x), ldv2(rw2 + 2 * (hb + 2 * p)), rr);
            rr = fma2(splat(u.y), ldv2(rw2 + 2 * (hb + 2 * p) + 2), rr);
        }
    }
    rrL[pair][h][kk][t] = t ? rr.y : rr.x;   // both lanes hold identical rr
    __syncthreads();
    {
        v2 rro = ldv2(&rrL[pair][h ^ 1][kk][0]);
        rr += rro;                            // full rho output everywhere
    }

    // ---- psi: ROLLED chunk loop ----
    v2 ee = (hu == 0) ? ldv2(psi_b2) : splat(0.f);
#pragma unroll 1
    for (int c = 0; c < 4; ++c) {
        const int hb = 8 * c;
#pragma unroll
        for (int p = 0; p < 4; ++p) {
            v2 tv = fma2(splat(rr.x), ldv2(sw1 + hb + 2 * p),
                    fma2(splat(rr.y), ldv2(sw1 + 64 + hb + 2 * p),
                    fma2(splat(g0),   ldv2(sw1 + 128 + hb + 2 * p),
                    fma2(splat(g1),   ldv2(sw1 + 192 + hb + 2 * p),
                                      ldv2(sb1 + hb + 2 * p)))));
            v2 u = relu2(tv);
            ee = fma2(splat(u.x), ldv2(sw2 + 2 * (hb + 2 * p)), ee);
            ee = fma2(splat(u.y), ldv2(sw2 + 2 * (hb + 2 * p) + 2), ee);
        }
    }
    eeL[pair][h][kk][t] = t ? ee.y : ee.x;
    __syncthreads();

    if (hu == 0 && t == 0 && valid) {
        v2 eeo = ldv2(&eeL[pair][1][kk][0]);
        float a0 = tanhf(tanhf(ee.x + eeo.x) + bar0);
        float a1 = tanhf(tanhf(ee.y + eeo.y) + bar1);
        out[s] = make_float2(2.f * a0, 2.f * a1);
    }
}

extern "C" void kernel_launch(void* const* d_in, const int* in_sizes, int n_in,
                              void* d_out, int out_size, void* d_ws, size_t ws_size,
                              hipStream_t stream) {
    dim3 grid((BATCH + 63) / 64), block(256);   // 64 samples per block
    barrier_net<<<grid, block, 0, stream>>>(
        (const float*)d_in[0],
        (const float*)d_in[1],  (const float*)d_in[2],  (const float*)d_in[3],  (const float*)d_in[4],
        (const float*)d_in[5],  (const float*)d_in[6],  (const float*)d_in[7],  (const float*)d_in[8],
        (const float*)d_in[9],  (const float*)d_in[10], (const float*)d_in[11], (const float*)d_in[12],
        (const float*)d_in[13], (const float*)d_in[14], (const float*)d_in[15], (const float*)d_in[16],
        (float2*)d_out);
}

// Round 10
// 143.598 us; speedup vs baseline: 1.6433x; 1.0019x over previous
//
#include <hip/hip_runtime.h>

#define BATCH 100000

typedef float v2 __attribute__((ext_vector_type(2)));

__device__ __forceinline__ v2 fma2(v2 a, v2 b, v2 c) { return __builtin_elementwise_fma(a, b, c); }
__device__ __forceinline__ v2 relu2(v2 a) { v2 z = {0.f, 0.f}; return __builtin_elementwise_max(a, z); }
__device__ __forceinline__ v2 splat(float a) { v2 r = {a, a}; return r; }
__device__ __forceinline__ v2 ldv2(const float* p) { return *(const v2*)p; }

// R18 = R11 VERBATIM except phi_w2/obs_w2 (8 KB = half of all weight
// bytes) served from LDS; everything else stays s_load.
// Theory revision: R8->R11 doubled waves covering a halved stream and
// gained only 8% -> the wall is NOT unoverlapped latency; it is a
// SHARED throughput limit all waves queue behind: the 16 KB scalar L1.
// Weight set = 17.1 KB > 16 KB -> every wave's ~130 s_load bursts miss
// to L2 through a shallow miss queue; VALUBusy pinned ~50% on lgkmcnt.
// (Consistent with R12/R17 nulls: total traffic and code size don't
// matter to a capacity-thrash wall.) Moving the two 64x16 W2 matrices
// to LDS leaves a 9.1 KB scalar set (FITS K$ -> W1/rho/psi become
// hits); W2 reads become wave-uniform ds_read broadcasts
// (conflict-free, pipelined under the full unroll).
// Unlike R14 (everything in LDS, register catastrophe): +2 base
// pointers on R11's proven ~60-VGPR live set, nothing else changes.
// readfirstlane(h) kept (R9/R10). Spill tripwire: WRITE_SIZE.
__global__ __launch_bounds__(256, 4) void barrier_net(
    const float* __restrict__ x,
    const float* __restrict__ phi_w1, const float* __restrict__ phi_b1,
    const float* __restrict__ phi_w2, const float* __restrict__ phi_b2,
    const float* __restrict__ obs_w1, const float* __restrict__ obs_b1,
    const float* __restrict__ obs_w2, const float* __restrict__ obs_b2,
    const float* __restrict__ rho_w1, const float* __restrict__ rho_b1,
    const float* __restrict__ rho_w2, const float* __restrict__ rho_b2,
    const float* __restrict__ psi_w1, const float* __restrict__ psi_b1,
    const float* __restrict__ psi_w2, const float* __restrict__ psi_b2,
    float2* __restrict__ out)
{
    __shared__ float W2L[2048];          // [0,1024) phi_w2, [1024,2048) obs_w2
    __shared__ float accL[2][2][32][16];
    __shared__ float rrL[2][2][32][2];
    __shared__ float eeL[2][2][32][2];

    // ---- cooperative W2 copy (overlaps the nb/ob global loads below) ----
    {
        const int i = threadIdx.x;
#pragma unroll
        for (int k = 0; k < 4; ++k) {
            W2L[i + 256 * k]        = phi_w2[i + 256 * k];
            W2L[1024 + i + 256 * k] = obs_w2[i + 256 * k];
        }
    }

    const int lane = threadIdx.x & 63;
    const int wave = threadIdx.x >> 6;
    const int pair = wave >> 1;
    const int h    = wave & 1;       // hidden half owned by this wave
    const int kk   = lane >> 1;      // sample index within the pair-group
    const int t    = lane & 1;       // lane half within the sample
    int s = blockIdx.x * 64 + pair * 32 + kk;
    const bool valid = (s < BATCH);
    if (!valid) s = BATCH - 1;       // clamp: keep loads in-bounds, stay for syncs
    const float* xr = x + (size_t)s * 85;

    // ---- uniform hidden-slice base pointers (readfirstlane: R9/R10) ----
    const int HB = __builtin_amdgcn_readfirstlane(h) * 32;
    const int hu = HB >> 5;
    const float* pw1 = phi_w1 + HB;                 // row stride 64
    const float* pb1 = phi_b1 + HB;
    const float* pw2 = W2L + HB * 16;               // W2 row slice (LDS)
    const float* qw1 = obs_w1 + HB;
    const float* qb1 = obs_b1 + HB;
    const float* qw2 = W2L + 1024 + HB * 16;        // W2 row slice (LDS)
    const float* rw1 = rho_w1 + HB;                 // row stride 64
    const float* rb1 = rho_b1 + HB;
    const float* rw2 = rho_w2 + (size_t)HB * 2;
    const float* sw1 = psi_w1 + HB;
    const float* sb1 = psi_b1 + HB;
    const float* sw2 = psi_w2 + (size_t)HB * 2;

    // ---- per-lane slice: 8 neighbors ----
    float nb[8][4];
    const int nbase = 5 + 32 * t;
#pragma unroll
    for (int n = 0; n < 8; ++n)
#pragma unroll
        for (int k = 0; k < 4; ++k)
            nb[n][k] = xr[nbase + 4 * n + k];

    // ---- barrier partial: wave 0 only (it does the final store) ----
    float bar0 = 0.f, bar1 = 0.f;
    if (hu == 0) {
#pragma unroll
        for (int n = 0; n < 8; ++n) {
            float p0 = -nb[n][0], p1 = -nb[n][1];
            float r  = __builtin_amdgcn_sqrtf(fmaf(p0, p0, p1 * p1));
            float sc = 0.01f * __builtin_amdgcn_rcpf(r - 0.2f);
            bar0 = fmaf(sc, p0, bar0);
            bar1 = fmaf(sc, p1, bar1);
        }
        bar0 += __shfl_xor(bar0, 1);
        bar1 += __shfl_xor(bar1, 1);
    }

    __syncthreads();   // W2L staged (placed after nb/barrier for overlap)

    // ---- acc partial: each of the 4 units carries 1/4 of the bias totals ----
    v2 acc[8];
#pragma unroll
    for (int p = 0; p < 8; ++p)
        acc[p] = fma2(splat(4.f), ldv2(phi_b2 + 2 * p),
                 fma2(splat(2.f), ldv2(obs_b2 + 2 * p), splat(0.f)));

    // ---- phi: 4 chunks of 8 hidden; W1 via s_load, W2 via LDS ----
#pragma unroll 2
    for (int c = 0; c < 4; ++c) {
        const int hb = 8 * c;
        v2 hsv[4] = {{0.f,0.f},{0.f,0.f},{0.f,0.f},{0.f,0.f}};
#pragma unroll
        for (int n = 0; n < 8; ++n) {
#pragma unroll
            for (int p = 0; p < 4; ++p) {
                v2 tv = fma2(splat(nb[n][0]), ldv2(pw1 + hb + 2 * p),
                        fma2(splat(nb[n][1]), ldv2(pw1 + 64 + hb + 2 * p),
                        fma2(splat(nb[n][2]), ldv2(pw1 + 128 + hb + 2 * p),
                        fma2(splat(nb[n][3]), ldv2(pw1 + 192 + hb + 2 * p),
                                              ldv2(pb1 + hb + 2 * p)))));
                hsv[p] += relu2(tv);
            }
        }
#pragma unroll
        for (int p = 0; p < 4; ++p) {
            const float* r0 = pw2 + (hb + 2 * p) * 16;
            v2 hx = splat(hsv[p].x), hy = splat(hsv[p].y);
#pragma unroll
            for (int q = 0; q < 8; ++q)
                acc[q] = fma2(hy, ldv2(r0 + 16 + 2 * q),
                         fma2(hx, ldv2(r0 + 2 * q), acc[q]));
        }
    }

    // ---- per-lane slice: 4 observations ----
    float ob[4][2];
    const int obase = 69 + 8 * t;
#pragma unroll
    for (int o = 0; o < 4; ++o) {
        ob[o][0] = xr[obase + 2 * o];
        ob[o][1] = xr[obase + 2 * o + 1];
    }

    // ---- obs: same chunking; W2 via LDS ----
#pragma unroll 2
    for (int c = 0; c < 4; ++c) {
        const int hb = 8 * c;
        v2 hsv[4] = {{0.f,0.f},{0.f,0.f},{0.f,0.f},{0.f,0.f}};
#pragma unroll
        for (int o = 0; o < 4; ++o) {
#pragma unroll
            for (int p = 0; p < 4; ++p) {
                v2 tv = fma2(splat(ob[o][0]), ldv2(qw1 + hb + 2 * p),
                        fma2(splat(ob[o][1]), ldv2(qw1 + 64 + hb + 2 * p),
                                              ldv2(qb1 + hb + 2 * p)));
                hsv[p] += relu2(tv);
            }
        }
#pragma unroll
        for (int p = 0; p < 4; ++p) {
            const float* r0 = qw2 + (hb + 2 * p) * 16;
            v2 hx = splat(hsv[p].x), hy = splat(hsv[p].y);
#pragma unroll
            for (int q = 0; q < 8; ++q)
                acc[q] = fma2(hy, ldv2(r0 + 16 + 2 * q),
                         fma2(hx, ldv2(r0 + 2 * q), acc[q]));
        }
    }

    // ---- combine across the lane pair (t) ----
#pragma unroll
    for (int p = 0; p < 8; ++p) {
        acc[p].x += __shfl_xor(acc[p].x, 1);
        acc[p].y += __shfl_xor(acc[p].y, 1);
    }

    // ---- combine across the wave pair (h) via LDS ----
    {
        float* slot = &accL[pair][h][kk][8 * t];
#pragma unroll
        for (int p = 0; p < 4; ++p) {
            v2 lo = acc[p], hi = acc[p + 4];
            v2 sel;
            sel.x = t ? hi.x : lo.x;
            sel.y = t ? hi.y : lo.y;
            *(v2*)(slot + 2 * p) = sel;
        }
    }
    __syncthreads();
    {
        const float* oslot = &accL[pair][h ^ 1][kk][0];
#pragma unroll
        for (int p = 0; p < 8; ++p)
            acc[p] += ldv2(oslot + 2 * p);
    }

    const float g0 = xr[0], g1 = xr[1];

    // ---- rho: 16 -> hidden slice -> 2 (partial); s_load weights ----
    v2 rr = (hu == 0) ? ldv2(rho_b2) : splat(0.f);
#pragma unroll 2
    for (int c = 0; c < 4; ++c) {
        const int hb = 8 * c;
        v2 tt[4];
#pragma unroll
        for (int p = 0; p < 4; ++p)
            tt[p] = ldv2(rb1 + hb + 2 * p);
#pragma unroll
        for (int j = 0; j < 8; ++j) {
            v2 ax = splat(acc[j].x), ay = splat(acc[j].y);
            const float* rj0 = rw1 + (size_t)(2 * j) * 64 + hb;
            const float* rj1 = rw1 + (size_t)(2 * j + 1) * 64 + hb;
#pragma unroll
            for (int p = 0; p < 4; ++p)
                tt[p] = fma2(ay, ldv2(rj1 + 2 * p),
                        fma2(ax, ldv2(rj0 + 2 * p), tt[p]));
        }
#pragma unroll
        for (int p = 0; p < 4; ++p) {
            v2 u = relu2(tt[p]);
            rr = fma2(splat(u.x), ldv2(rw2 + 2 * (hb + 2 * p)), rr);
            rr = fma2(splat(u.y), ldv2(rw2 + 2 * (hb + 2 * p) + 2), rr);
        }
    }
    rrL[pair][h][kk][t] = t ? rr.y : rr.x;   // both lanes hold identical rr
    __syncthreads();
    {
        v2 rro = ldv2(&rrL[pair][h ^ 1][kk][0]);
        rr += rro;                            // full rho output everywhere
    }

    // ---- psi: [r0, r1, g0, g1] -> hidden slice -> 2 (partial) ----
    v2 ee = (hu == 0) ? ldv2(psi_b2) : splat(0.f);
#pragma unroll 2
    for (int c = 0; c < 4; ++c) {
        const int hb = 8 * c;
#pragma unroll
        for (int p = 0; p < 4; ++p) {
            v2 tv = fma2(splat(rr.x), ldv2(sw1 + hb + 2 * p),
                    fma2(splat(rr.y), ldv2(sw1 + 64 + hb + 2 * p),
                    fma2(splat(g0),   ldv2(sw1 + 128 + hb + 2 * p),
                    fma2(splat(g1),   ldv2(sw1 + 192 + hb + 2 * p),
                                      ldv2(sb1 + hb + 2 * p)))));
            v2 u = relu2(tv);
            ee = fma2(splat(u.x), ldv2(sw2 + 2 * (hb + 2 * p)), ee);
            ee = fma2(splat(u.y), ldv2(sw2 + 2 * (hb + 2 * p) + 2), ee);
        }
    }
    eeL[pair][h][kk][t] = t ? ee.y : ee.x;
    __syncthreads();

    if (hu == 0 && t == 0 && valid) {
        v2 eeo = ldv2(&eeL[pair][1][kk][0]);
        float a0 = tanhf(tanhf(ee.x + eeo.x) + bar0);
        float a1 = tanhf(tanhf(ee.y + eeo.y) + bar1);
        out[s] = make_float2(2.f * a0, 2.f * a1);
    }
}

extern "C" void kernel_launch(void* const* d_in, const int* in_sizes, int n_in,
                              void* d_out, int out_size, void* d_ws, size_t ws_size,
                              hipStream_t stream) {
    dim3 grid((BATCH + 63) / 64), block(256);   // 64 samples per block
    barrier_net<<<grid, block, 0, stream>>>(
        (const float*)d_in[0],
        (const float*)d_in[1],  (const float*)d_in[2],  (const float*)d_in[3],  (const float*)d_in[4],
        (const float*)d_in[5],  (const float*)d_in[6],  (const float*)d_in[7],  (const float*)d_in[8],
        (const float*)d_in[9],  (const float*)d_in[10], (const float*)d_in[11], (const float*)d_in[12],
        (const float*)d_in[13], (const float*)d_in[14], (const float*)d_in[15], (const float*)d_in[16],
        (float2*)d_out);
}